// Round 4
// baseline (3352.790 us; speedup 1.0000x reference)
//
#include <hip/hip_runtime.h>
#include <hip/hip_bf16.h>
#include <type_traits>

#define B_   64
#define T_   48
#define H_   512
#define E_   512
#define ATT_ 196
#define AF_  2048
#define FC_  2048
#define V_   10000

typedef unsigned short u16;
using s16x8 = __attribute__((ext_vector_type(8))) short;
using f32x4 = __attribute__((ext_vector_type(4))) float;

// input-storage modes for GEMM/pointwise loaders
#define MD_BF16 0
#define MD_F32  1
#define MD_DYN  2   // resolve from detected flag (d_in float tensors)

__device__ __forceinline__ float b2f(u16 u) {
  union { unsigned int i; float f; } x; x.i = ((unsigned int)u) << 16; return x.f;
}
__device__ __forceinline__ u16 f2b(float f) {
  union { float f; unsigned int i; } x; x.f = f;
  unsigned int r = x.i + 0x7fffu + ((x.i >> 16) & 1u);
  return (u16)(r >> 16);
}
__device__ __forceinline__ float sigmoid_(float x) { return 1.f / (1.f + __expf(-x)); }
__device__ __forceinline__ float tanh_(float x) { return 1.f - 2.f / (__expf(2.f * x) + 1.f); }

// pointwise load of a "float tensor" whose storage is f32 (f=1) or bf16 (f=0)
__device__ __forceinline__ float ldf(const void* p, size_t i, int f) {
  return f ? ((const float*)p)[i] : b2f(((const u16*)p)[i]);
}
// 8-element fragment load -> bf16x8 (converts if storage is f32)
__device__ __forceinline__ s16x8 ld8(const void* p, size_t idx, int f) {
  s16x8 r;
  if (f) {
    const float* q = (const float*)p + idx;
    float4 x = *(const float4*)q;
    float4 y = *(const float4*)(q + 4);
    r[0] = (short)f2b(x.x); r[1] = (short)f2b(x.y);
    r[2] = (short)f2b(x.z); r[3] = (short)f2b(x.w);
    r[4] = (short)f2b(y.x); r[5] = (short)f2b(y.y);
    r[6] = (short)f2b(y.z); r[7] = (short)f2b(y.w);
  } else {
    r = *(const s16x8*)((const u16*)p + idx);
  }
  return r;
}
__device__ __forceinline__ s16x8 zero8() {
  s16x8 r; for (int j = 0; j < 8; j++) r[j] = 0; return r;
}

// storage detector: f32 storage => u16 view of att_feats contains exponent-0xFF
// bit patterns (random mantissa halves) with certainty; bf16 N(0,1) never does.
__global__ void detect_f32(const u16* __restrict__ p, int* __restrict__ flag) {
  __shared__ int sb[256];
  int t = threadIdx.x, bad = 0;
  for (int i = t; i < 65536; i += 256) {
    int e = (p[i] >> 7) & 0xFF;
    bad |= (e == 0xFF) ? 1 : 0;
  }
  sb[t] = bad; __syncthreads();
  for (int s = 128; s; s >>= 1) { if (t < s) sb[t] |= sb[t + s]; __syncthreads(); }
  if (t == 0) *flag = sb[0];
}

// ---------------------------------------------------------------------------
// NT GEMM: C[M x N] = A[M x K] * B[N x K]^T (+bias), bf16 MFMA, f32 acc.
// A/B storage per amode/bmode (bf16 / f32 / dynamic-flag); f32 operands are
// converted to bf16 in registers during LDS staging. Block tile 64x64
// (4 waves x 32x32), BK=32. grid.z = split-K; z-slice covers Kc K-columns,
// writes partial to C + z*zstride (bias only on z==0). M multiple of 64.
// ---------------------------------------------------------------------------
template <typename CT>
__global__ __launch_bounds__(256) void gemm_nt(
    const void* __restrict__ A, int lda, size_t aoff, int amode,
    const void* __restrict__ B, int ldb, size_t boff, int bmode,
    CT* __restrict__ C, int ldc, int N, int Kc,
    const float* __restrict__ bias, size_t zstride, const int* __restrict__ flagp)
{
  __shared__ __align__(16) u16 As[64 * 40];  // row stride 40: 16B-aligned + pad
  __shared__ __align__(16) u16 Bs[64 * 40];

  const int dynf = *flagp;
  const int aF = (amode == MD_DYN) ? dynf : amode;
  const int bF = (bmode == MD_DYN) ? dynf : bmode;

  const int tid  = threadIdx.x;
  const int m0   = blockIdx.x * 64;
  const int n0   = blockIdx.y * 64;
  const int kz   = blockIdx.z * Kc;
  const int lane = tid & 63;
  const int w    = tid >> 6;
  const int wm   = (w >> 1) * 32;
  const int wn   = (w & 1) * 32;
  const int quad = lane >> 4;
  const int r16  = lane & 15;

  f32x4 acc[2][2];
  for (int a = 0; a < 2; a++) for (int b = 0; b < 2; b++)
    for (int k = 0; k < 4; k++) acc[a][b][k] = 0.f;

  const int sr = tid >> 2;        // staged tile row 0..63
  const int sc = (tid & 3) * 8;   // 0,8,16,24
  const size_t idxA = (size_t)(m0 + sr) * lda + aoff + kz + sc;
  const size_t idxB = (size_t)(n0 + sr) * ldb + boff + kz + sc;
  const bool bok = (n0 + sr) < N;

  const int aoff0 = (wm + r16) * 40 + quad * 8;
  const int aoff1 = (wm + 16 + r16) * 40 + quad * 8;
  const int boff0 = (wn + r16) * 40 + quad * 8;
  const int boff1 = (wn + 16 + r16) * 40 + quad * 8;

  s16x8 av = ld8(A, idxA, aF);
  s16x8 bv = bok ? ld8(B, idxB, bF) : zero8();

  for (int k0 = 0; k0 < Kc; k0 += 32) {
    s16x8 avn = zero8(), bvn = zero8();
    if (k0 + 32 < Kc) {  // prefetch next K-slab
      avn = ld8(A, idxA + k0 + 32, aF);
      if (bok) bvn = ld8(B, idxB + k0 + 32, bF);
    }
    __syncthreads();
    *(s16x8*)(As + sr * 40 + sc) = av;
    *(s16x8*)(Bs + sr * 40 + sc) = bv;
    __syncthreads();
    s16x8 a0 = *(const s16x8*)(As + aoff0);
    s16x8 a1 = *(const s16x8*)(As + aoff1);
    s16x8 b0 = *(const s16x8*)(Bs + boff0);
    s16x8 b1 = *(const s16x8*)(Bs + boff1);
    acc[0][0] = __builtin_amdgcn_mfma_f32_16x16x32_bf16(a0, b0, acc[0][0], 0, 0, 0);
    acc[0][1] = __builtin_amdgcn_mfma_f32_16x16x32_bf16(a0, b1, acc[0][1], 0, 0, 0);
    acc[1][0] = __builtin_amdgcn_mfma_f32_16x16x32_bf16(a1, b0, acc[1][0], 0, 0, 0);
    acc[1][1] = __builtin_amdgcn_mfma_f32_16x16x32_bf16(a1, b1, acc[1][1], 0, 0, 0);
    av = avn; bv = bvn;
  }

  CT* Cz = C + (size_t)blockIdx.z * zstride;
  const bool addb = (bias != nullptr) && (blockIdx.z == 0);
  for (int tm = 0; tm < 2; tm++)
    for (int tn = 0; tn < 2; tn++) {
      int col = n0 + wn + tn * 16 + r16;          // C/D: col = lane&15
      if (col >= N) continue;
      float bb = addb ? bias[col] : 0.f;
      int rowbase = m0 + wm + tm * 16 + quad * 4; // C/D: row = quad*4 + reg
      for (int rg = 0; rg < 4; rg++) {
        float v = acc[tm][tn][rg] + bb;
        if constexpr (std::is_same<CT, float>::value)
          Cz[(size_t)(rowbase + rg) * ldc + col] = v;
        else
          Cz[(size_t)(rowbase + rg) * ldc + col] = f2b(v);
      }
    }
}

// --- weight/bias packing (reads d_in floats via flag) ------------------------
__global__ __launch_bounds__(256) void pack_wstep(
    const void* __restrict__ wH, const void* __restrict__ wI,
    const void* __restrict__ wf1, const void* __restrict__ wf2,
    u16* __restrict__ Wstep, const int* __restrict__ flagp)
{
  // Wstep[2560][2048] over cat4=[x_a|x_f|h_a|h_f]:
  // rows 0..1023 weight_H; 1024..1535 weight_I[:, :2048];
  // 1536..2047 f1 (x1->0:512, h1->1024:1536); 2048..2559 f2 (x2->512:1024, h2->1536:2048)
  const int F = *flagp;
  for (int idx = blockIdx.x * 256 + threadIdx.x; idx < 2560 * 2048; idx += gridDim.x * 256) {
    int row = idx >> 11, col = idx & 2047;
    float v = 0.f;
    if (row < 1024) v = ldf(wH, (size_t)row * 2048 + col, F);
    else if (row < 1536) v = ldf(wI, (size_t)(row - 1024) * 4096 + col, F);
    else if (row < 2048) {
      int r = row - 1536;
      if (col < 512) v = ldf(wf1, (size_t)r * 1024 + col, F);
      else if (col >= 1024 && col < 1536) v = ldf(wf1, (size_t)r * 1024 + 512 + (col - 1024), F);
    } else {
      int r = row - 2048;
      if (col >= 512 && col < 1024) v = ldf(wf2, (size_t)r * 1024 + (col - 512), F);
      else if (col >= 1536) v = ldf(wf2, (size_t)r * 1024 + 512 + (col - 1536), F);
    }
    Wstep[idx] = f2b(v);
  }
}

__global__ __launch_bounds__(256) void pack_whahf(
    const void* __restrict__ W_ha, const void* __restrict__ W_hf,
    u16* __restrict__ Whahf, const int* __restrict__ flagp)
{
  const int F = *flagp;
  for (int idx = blockIdx.x * 256 + threadIdx.x; idx < 512 * 1024; idx += gridDim.x * 256) {
    int e = idx >> 10, k = idx & 1023;
    float v = (k < 512) ? ldf(W_ha, (size_t)e * 512 + k, F)
                        : ldf(W_hf, (size_t)e * 512 + (k - 512), F);
    Whahf[idx] = f2b(v);
  }
}

__global__ __launch_bounds__(256) void pack_bias(
    const void* bH, const void* bI, const void* bf1, const void* bf2,
    const void* bha, const void* bhf, const void* batt, const void* bfc, const void* blogit,
    float* biasStep, float* bhahf, float* batt_f, float* bfc_f, float* blogit_f,
    const int* __restrict__ flagp)
{
  const int F = *flagp;
  int t = blockIdx.x * 256 + threadIdx.x;
  if (t < 1024) biasStep[t] = ldf(bH, t, F);
  else if (t < 1536) biasStep[t] = ldf(bI, t - 1024, F);
  else if (t < 2048) biasStep[t] = ldf(bf1, t - 1536, F);
  else if (t < 2560) biasStep[t] = ldf(bf2, t - 2048, F);
  if (t < 512) {
    bhahf[t] = ldf(bha, t, F) + ldf(bhf, t, F);
    batt_f[t] = ldf(batt, t, F);
    bfc_f[t] = ldf(bfc, t, F);
  }
  if (t < V_) blogit_f[t] = ldf(blogit, t, F);
}

// cat4 for step 0: x_a = fc_emb, x_f = h_a = h_f = 0
__global__ __launch_bounds__(256) void init_cat4(const float* __restrict__ fc_emb,
                                                 u16* __restrict__ cat4)
{
  int b = blockIdx.x, tid = threadIdx.x;
  u16* cr = cat4 + b * 2048;
  for (int rep = 0; rep < 2; rep++) {
    int j = tid + rep * 256;
    cr[j] = f2b(fc_emb[b * E_ + j]);
    cr[512 + j] = 0; cr[1024 + j] = 0; cr[1536 + j] = 0;
  }
}

// attention logits: alog[b,a] = sum_e W_alpha[e]*tanh(tatf[b,e] + p_att[b,a,e]) + b_alpha
__global__ __launch_bounds__(256) void att_logits_kernel(
    const float* __restrict__ tatf, const u16* __restrict__ p_att,
    const void* __restrict__ W_alpha, const void* __restrict__ b_alpha,
    float* __restrict__ alog, const int* __restrict__ flagp)
{
  const int F = *flagp;
  int gw = (blockIdx.x * 256 + threadIdx.x) >> 6;   // one wave per (b,a)
  int lane = threadIdx.x & 63;
  if (gw >= B_ * ATT_) return;
  int b = gw / ATT_;
  const float* tr = tatf + b * H_;
  const u16* pr = p_att + (size_t)gw * H_;
  float acc = 0.f;
#pragma unroll
  for (int e0 = 0; e0 < H_; e0 += 64) {
    int e = e0 + lane;
    acc += tanh_(tr[e] + b2f(pr[e])) * ldf(W_alpha, e, F);
  }
#pragma unroll
  for (int off = 32; off; off >>= 1) acc += __shfl_down(acc, off);
  if (lane == 0) alog[gw] = acc + ldf(b_alpha, 0, F);
}

// softmax over a (196) + weighted sum of att_proj -> outc[b, seg*64 + lane]
// alog == nullptr => uniform 1/196 (att_mean precompute)
__global__ __launch_bounds__(256) void att_apply_kernel(
    const float* __restrict__ alog, const u16* __restrict__ att_proj,
    float* __restrict__ outc)
{
  int b = blockIdx.x, seg = blockIdx.y, tid = threadIdx.x;
  __shared__ float sw[ATT_];
  __shared__ float rb[256];
  if (alog) {
    float l = (tid < ATT_) ? alog[b * ATT_ + tid] : -3.0e38f;
    rb[tid] = l; __syncthreads();
    for (int s = 128; s; s >>= 1) { if (tid < s) rb[tid] = fmaxf(rb[tid], rb[tid + s]); __syncthreads(); }
    float mx = rb[0]; __syncthreads();
    float e = (tid < ATT_) ? __expf(l - mx) : 0.f;
    rb[tid] = e; __syncthreads();
    for (int s = 128; s; s >>= 1) { if (tid < s) rb[tid] += rb[tid + s]; __syncthreads(); }
    float sum = rb[0]; __syncthreads();
    if (tid < ATT_) sw[tid] = e / sum;
  } else {
    if (tid < ATT_) sw[tid] = 1.f / (float)ATT_;
  }
  __syncthreads();
  int lane = tid & 63, g = tid >> 6;
  int col = seg * 64 + lane;
  float acc = 0.f;
  for (int a = g; a < ATT_; a += 4)
    acc += sw[a] * b2f(att_proj[(size_t)(b * ATT_ + a) * H_ + col]);
  rb[tid] = acc; __syncthreads();
  if (g == 0) outc[b * H_ + col] = rb[lane] + rb[64 + lane] + rb[128 + lane] + rb[192 + lane];
}

// LSTM cell epilogue + fused build of next step's cat4.
// Gbuf: 4 split-K slices [z][b][2560]; cols 0:512 in, 512:1024 out,
// 1024:1536 cellgate(pre-att), 1536:2048 f1, 2048:2560 f2.
__global__ __launch_bounds__(256) void step_finish_kernel(
    const float* __restrict__ Gbuf, const float* __restrict__ attc,
    float* __restrict__ c_states, u16* __restrict__ houts, u16* __restrict__ cat4,
    const int* __restrict__ father_idx, const int* __restrict__ word_idx,
    const void* __restrict__ embed_tab,
    int i, int is_first, int use_f, int build_next, int use_f_next,
    const int* __restrict__ flagp)
{
  const int F = *flagp;
  int b = blockIdx.x, tid = threadIdx.x;
  __shared__ u16 nh_sh[H_];
  int father = father_idx[b * T_ + i];
  const float* G0 = Gbuf + (size_t)b * 2560;
  const size_t zs = (size_t)B_ * 2560;
#pragma unroll
  for (int rep = 0; rep < 2; rep++) {
    int j = tid + rep * 256;
    float g_in = G0[j] + G0[zs + j] + G0[2 * zs + j] + G0[3 * zs + j];
    float g_out = G0[512 + j] + G0[zs + 512 + j] + G0[2 * zs + 512 + j] + G0[3 * zs + 512 + j];
    float g_cg = G0[1024 + j] + G0[zs + 1024 + j] + G0[2 * zs + 1024 + j] + G0[3 * zs + 1024 + j];
    float g_f1 = G0[1536 + j] + G0[zs + 1536 + j] + G0[2 * zs + 1536 + j] + G0[3 * zs + 1536 + j];
    float g_f2 = G0[2048 + j] + G0[zs + 2048 + j] + G0[2 * zs + 2048 + j] + G0[3 * zs + 2048 + j];
    float ing = sigmoid_(g_in);
    float outg = sigmoid_(g_out);
    float cg = tanh_(g_cg + attc[b * H_ + j]);
    float f1 = sigmoid_(g_f1);
    float f2 = sigmoid_(g_f2);
    // father==i (or future) reads the memset zeros, matching reference scan state
    float c1 = is_first ? 0.f : c_states[((size_t)b * T_ + father) * H_ + j];
    float c2 = use_f ? c_states[((size_t)b * T_ + (i - 1)) * H_ + j] : 0.f;
    float nc = f1 * c1 + f2 * c2 + ing * cg;
    float nh = outg * tanh_(nc);
    size_t o = ((size_t)b * T_ + i) * H_ + j;
    c_states[o] = nc;
    u16 hb = f2b(nh);
    houts[o] = hb;
    nh_sh[j] = hb;
  }
  __syncthreads();
  if (!build_next) return;
  int fn = father_idx[b * T_ + (i + 1)];
  int wa = word_idx[b * T_ + fn];
  int wf = word_idx[b * T_ + i];
  u16* cr = cat4 + b * 2048;
#pragma unroll
  for (int rep = 0; rep < 2; rep++) {
    int j = tid + rep * 256;
    cr[j] = f2b(ldf(embed_tab, (size_t)wa * E_ + j, F));                       // x_a
    cr[512 + j] = use_f_next ? f2b(ldf(embed_tab, (size_t)wf * E_ + j, F)) : (u16)0; // x_f
    // h_a: fn==i -> just-computed nh (LDS); fn>i -> memset zeros; fn<i -> prior steps
    cr[1024 + j] = (fn == i) ? nh_sh[j] : houts[((size_t)b * T_ + fn) * H_ + j];
    cr[1536 + j] = use_f_next ? nh_sh[j] : (u16)0;                             // h_f
  }
}

// in-place log_softmax over V=10000 per row of d_out (f32)
__global__ __launch_bounds__(256) void logsoftmax_kernel(float* __restrict__ out)
{
  __shared__ float vals[V_];
  __shared__ float rb[256];
  int row = blockIdx.x, tid = threadIdx.x;
  float* p = out + (size_t)row * V_;
  float mx = -3.0e38f;
  for (int c = tid * 4; c < V_; c += 1024) {   // V_=10000: last stride exact-fits
    float4 q = *(const float4*)(p + c);
    vals[c] = q.x; vals[c + 1] = q.y; vals[c + 2] = q.z; vals[c + 3] = q.w;
    mx = fmaxf(mx, fmaxf(fmaxf(q.x, q.y), fmaxf(q.z, q.w)));
  }
  rb[tid] = mx; __syncthreads();
  for (int s = 128; s; s >>= 1) { if (tid < s) rb[tid] = fmaxf(rb[tid], rb[tid + s]); __syncthreads(); }
  mx = rb[0]; __syncthreads();
  float sum = 0.f;
  for (int c = tid; c < V_; c += 256) sum += __expf(vals[c] - mx);
  rb[tid] = sum; __syncthreads();
  for (int s = 128; s; s >>= 1) { if (tid < s) rb[tid] += rb[tid + s]; __syncthreads(); }
  float lse = mx + __logf(rb[0]);
  for (int c = tid * 4; c < V_; c += 1024) {
    float4 q;
    q.x = vals[c] - lse; q.y = vals[c + 1] - lse;
    q.z = vals[c + 2] - lse; q.w = vals[c + 3] - lse;
    *(float4*)(p + c) = q;
  }
}

extern "C" void kernel_launch(void* const* d_in, const int* in_sizes, int n_in,
                              void* d_out, int out_size, void* d_ws, size_t ws_size,
                              hipStream_t stream)
{
  const int* word_idx   = (const int*)d_in[0];
  const int* father_idx = (const int*)d_in[1];
  const void* fc_feats  = d_in[2];
  const void* att_feats = d_in[3];
  const void* W_fc      = d_in[4];
  const void* b_fc      = d_in[5];
  const void* W_att     = d_in[6];
  const void* b_att     = d_in[7];
  const void* embed_tab = d_in[8];
  const void* weight_f1 = d_in[9];
  const void* bias_f1   = d_in[10];
  const void* weight_f2 = d_in[11];
  const void* bias_f2   = d_in[12];
  const void* weight_H  = d_in[13];
  const void* bias_H    = d_in[14];
  const void* weight_I  = d_in[15];
  const void* bias_I    = d_in[16];
  const void* W_ha      = d_in[17];
  const void* b_ha      = d_in[18];
  const void* W_hf      = d_in[19];
  const void* b_hf      = d_in[20];
  const void* W_alpha   = d_in[21];
  const void* b_alpha   = d_in[22];
  const void* W_logit   = d_in[23];
  const void* b_logit   = d_in[24];

  // ---- d_out is 30.72M f32 = 122.88 MB. All dead-before-logits scratch lives
  // here (~47 MB); the final logits GEMM reads nothing from d_out and then
  // overwrites it fully. Byte-offset allocator:
  char* dob = (char*)d_out;
  size_t doff = 0;
  auto oalloc = [&](size_t bytes) -> char* {
    char* p = dob + doff;
    doff += (bytes + 255) & ~(size_t)255;
    return p;
  };
  u16*  p_att    = (u16*)oalloc((size_t)B_ * ATT_ * E_ * 2);   // 12.85 MB
  u16*  att_proj = (u16*)oalloc((size_t)B_ * ATT_ * H_ * 2);   // 12.85 MB
  u16*  Wstep    = (u16*)oalloc((size_t)2560 * 2048 * 2);      // 10.49 MB
  u16*  Whahf    = (u16*)oalloc((size_t)512 * 1024 * 2);       //  1.05 MB
  float* c_states = (float*)oalloc((size_t)B_ * T_ * H_ * 4);  //  6.29 MB
  float* Gbuf     = (float*)oalloc((size_t)4 * B_ * 2560 * 4); //  2.62 MB
  u16*  cat4     = (u16*)oalloc((size_t)B_ * 2048 * 2);
  float* fc_emb   = (float*)oalloc((size_t)B_ * E_ * 4);
  float* att_meanp= (float*)oalloc((size_t)B_ * H_ * 4);
  float* tatf     = (float*)oalloc((size_t)B_ * H_ * 4);
  float* alog     = (float*)oalloc((size_t)B_ * ATT_ * 4);
  float* attc     = (float*)oalloc((size_t)B_ * H_ * 4);
  float* biasStep = (float*)oalloc(2560 * 4);
  float* bhahf    = (float*)oalloc(512 * 4);
  float* batt_f   = (float*)oalloc(512 * 4);
  float* bfc_f    = (float*)oalloc(512 * 4);
  // total ~47 MB < 122.88 MB ✓

  // ---- only buffers LIVE during the final logits GEMM go in d_ws (~3.2 MB) --
  char* ws = (char*)d_ws;
  size_t woff = 0;
  auto walloc = [&](size_t bytes) -> char* {
    char* p = ws + woff;
    woff += (bytes + 255) & ~(size_t)255;
    return p;
  };
  u16*  houts    = (u16*)walloc((size_t)B_ * T_ * H_ * 2);     // 3.15 MB
  float* blogit_f = (float*)walloc((size_t)V_ * 4);
  int*   flag     = (int*)walloc(256);

  hipMemsetAsync(c_states, 0, (size_t)B_ * T_ * H_ * 4, stream);
  hipMemsetAsync(houts, 0, (size_t)B_ * T_ * H_ * 2, stream);

  detect_f32<<<1, 256, 0, stream>>>((const u16*)att_feats, flag);

  pack_wstep<<<4096, 256, 0, stream>>>(weight_H, weight_I, weight_f1, weight_f2, Wstep, flag);
  pack_whahf<<<2048, 256, 0, stream>>>(W_ha, W_hf, Whahf, flag);
  pack_bias<<<40, 256, 0, stream>>>(bias_H, bias_I, bias_f1, bias_f2, b_ha, b_hf,
                                    b_att, b_fc, b_logit,
                                    biasStep, bhahf, batt_f, bfc_f, blogit_f, flag);

  // fc_emb = fc_feats @ W_fc^T + b_fc  (f32 out)
  gemm_nt<float><<<dim3(1, 8, 1), 256, 0, stream>>>(
      fc_feats, FC_, 0, MD_DYN, W_fc, FC_, 0, MD_DYN,
      fc_emb, E_, E_, FC_, bfc_f, 0, flag);
  // p_att = att_feats @ W_att^T + b_att  (bf16 out)
  gemm_nt<u16><<<dim3(B_ * ATT_ / 64, 8, 1), 256, 0, stream>>>(
      att_feats, AF_, 0, MD_DYN, W_att, AF_, 0, MD_DYN,
      p_att, E_, E_, AF_, batt_f, 0, flag);
  // att_proj = att_feats @ weight_I[:, 2048:4096]^T  (bf16 out, no bias)
  gemm_nt<u16><<<dim3(B_ * ATT_ / 64, 8, 1), 256, 0, stream>>>(
      att_feats, AF_, 0, MD_DYN, weight_I, 4096, 2048, MD_DYN,
      att_proj, H_, H_, AF_, nullptr, 0, flag);
  // att_mean contribution = mean_a att_proj
  att_apply_kernel<<<dim3(B_, 8), 256, 0, stream>>>(nullptr, att_proj, att_meanp);
  init_cat4<<<B_, 256, 0, stream>>>(fc_emb, cat4);

  for (int i = 0; i < T_; i++) {
    int is_first = (i == 0);
    int use_f = (!is_first && ((i - 1) % 3 != 0)) ? 1 : 0;
    if (!is_first) {
      // tatf = [h_a|h_f] @ [W_ha|W_hf]^T + (b_ha+b_hf)
      gemm_nt<float><<<dim3(1, 8, 1), 256, 0, stream>>>(
          cat4, 2048, 1024, MD_BF16, Whahf, 1024, 0, MD_BF16,
          tatf, H_, H_, 1024, bhahf, 0, flag);
      att_logits_kernel<<<(B_ * ATT_) / 4, 256, 0, stream>>>(
          tatf, p_att, W_alpha, b_alpha, alog, flag);
      att_apply_kernel<<<dim3(B_, 8), 256, 0, stream>>>(alog, att_proj, attc);
    }
    // step GEMM: [gates|cellgate|f1|f2] = cat4 @ Wstep^T + biasStep, split-K x4
    gemm_nt<float><<<dim3(1, 40, 4), 256, 0, stream>>>(
        cat4, 2048, 0, MD_BF16, Wstep, 2048, 0, MD_BF16,
        Gbuf, 2560, 2560, 512, biasStep, (size_t)B_ * 2560, flag);
    int build = (i + 1 < T_) ? 1 : 0;
    int use_f_next = (build && (i % 3 != 0)) ? 1 : 0;
    step_finish_kernel<<<B_, 256, 0, stream>>>(
        Gbuf, is_first ? att_meanp : attc, c_states, houts, cat4,
        father_idx, word_idx, embed_tab, i, is_first, use_f, build, use_f_next, flag);
  }

  // logits = houts @ W_logit^T + b_logit -> d_out (f32!), then in-place
  // log_softmax. Reads only houts/W_logit/blogit_f/flag (none in d_out).
  gemm_nt<float><<<dim3(B_ * T_ / 64, (V_ + 63) / 64, 1), 256, 0, stream>>>(
      houts, H_, 0, MD_BF16, W_logit, H_, 0, MD_DYN,
      (float*)d_out, V_, V_, H_, blogit_f, 0, flag);
  logsoftmax_kernel<<<B_ * T_, 256, 0, stream>>>((float*)d_out);
}